// Round 1
// baseline (410.492 us; speedup 1.0000x reference)
//
#include <hip/hip_runtime.h>
#include <math.h>

// Problem constants
#define BB   64
#define CC   256
#define HWQ  4096
#define TILE 64      // pixels per block in pass1
#define TPB  256

// Workspace layout (floats)
#define WS_BETA 0        // [B][C] sum_s x
#define WS_CTX  16384    // [B][C] sum_s x*exp(logit)
#define WS_Z    32768    // [B]    sum_s exp(logit)
#define WS_M    32832    // [B]    sum_s max_c x
#define WS_N    32896

__global__ void zero_ws(float* __restrict__ ws, int n) {
    int i = blockIdx.x * blockDim.x + threadIdx.x;
    if (i < n) ws[i] = 0.0f;
}

// Pass 1: single read of x. Per block: one (b, 64-pixel) tile.
//  - stage tile into LDS (float4, coalesced: 16 lanes x float4 = one channel row)
//  - logit & channel-max partials computed from registers during staging
//  - reduce partials -> per-pixel logit/cmax; p = exp(logit + b_mask)
//  - re-read tile from LDS (skewed, conflict-free) for per-channel sum / weighted sum
__global__ __launch_bounds__(TPB) void pass1(
    const float* __restrict__ x,
    const float* __restrict__ w_mask,
    const float* __restrict__ b_mask,
    float* __restrict__ ws)
{
    __shared__ __align__(16) float tileX[CC * TILE];   // 64 KB, [c][s], stride 64
    __shared__ __align__(16) float wm[CC];
    __shared__ __align__(16) float redL[16 * 16 * 4];  // [hi][j][k] logit partials
    __shared__ __align__(16) float redM[16 * 16 * 4];  // [hi][j][k] cmax partials
    __shared__ __align__(16) float tileP[TILE];

    float* beta_sum = ws + WS_BETA;
    float* ctx_sum  = ws + WS_CTX;
    float* Zsum     = ws + WS_Z;
    float* msum     = ws + WS_M;

    const int tid = threadIdx.x;
    const int b   = blockIdx.x >> 6;          // 64 tiles per batch
    const int t0  = (blockIdx.x & 63) * TILE; // pixel base

    wm[tid] = w_mask[tid];
    __syncthreads();

    const int hi = tid >> 4;   // 0..15 channel sub-index within a 16-channel group
    const int j  = tid & 15;   // 0..15 pixel-quad index
    const float* xb = x + (size_t)b * CC * HWQ;

    float lp0 = 0.f, lp1 = 0.f, lp2 = 0.f, lp3 = 0.f;
    float mp0 = -3.4e38f, mp1 = -3.4e38f, mp2 = -3.4e38f, mp3 = -3.4e38f;

    #pragma unroll
    for (int i = 0; i < 16; ++i) {
        const int c = i * 16 + hi;
        const float4 v = *reinterpret_cast<const float4*>(xb + (size_t)c * HWQ + t0 + 4 * j);
        *reinterpret_cast<float4*>(&tileX[c * TILE + 4 * j]) = v;
        const float w = wm[c];
        lp0 = fmaf(w, v.x, lp0); lp1 = fmaf(w, v.y, lp1);
        lp2 = fmaf(w, v.z, lp2); lp3 = fmaf(w, v.w, lp3);
        mp0 = fmaxf(mp0, v.x); mp1 = fmaxf(mp1, v.y);
        mp2 = fmaxf(mp2, v.z); mp3 = fmaxf(mp3, v.w);
    }
    reinterpret_cast<float4*>(redL)[tid] = make_float4(lp0, lp1, lp2, lp3);
    reinterpret_cast<float4*>(redM)[tid] = make_float4(mp0, mp1, mp2, mp3);
    __syncthreads();

    if (tid < TILE) {
        // pixel s = tid: combine 16 channel-partition partials
        float lg = 0.f, cm = -3.4e38f;
        #pragma unroll
        for (int h = 0; h < 16; ++h) {
            lg += redL[h * 64 + tid];
            cm = fmaxf(cm, redM[h * 64 + tid]);
        }
        lg += b_mask[0];
        const float p = expf(lg);   // logits ~N(0,0.64): raw exp is fp32-safe
        tileP[tid] = p;
        float zs = p, cs = cm;
        #pragma unroll
        for (int off = 32; off > 0; off >>= 1) {
            zs += __shfl_down(zs, off, 64);
            cs += __shfl_down(cs, off, 64);
        }
        if (tid == 0) {
            atomicAdd(&Zsum[b], zs);
            atomicAdd(&msum[b], cs);
        }
    }
    __syncthreads();

    // Phase B2: thread = channel; skewed float4 reads (conflict-free)
    {
        const int c = tid;
        const float4* xr = reinterpret_cast<const float4*>(&tileX[c * TILE]);
        const float4* pr = reinterpret_cast<const float4*>(tileP);
        float sm = 0.f, cx = 0.f;
        #pragma unroll
        for (int s4 = 0; s4 < 16; ++s4) {
            const int idx = (s4 + c) & 15;
            const float4 xv = xr[idx];
            const float4 pv = pr[idx];
            sm += xv.x + xv.y + xv.z + xv.w;
            cx = fmaf(xv.x, pv.x, cx); cx = fmaf(xv.y, pv.y, cx);
            cx = fmaf(xv.z, pv.z, cx); cx = fmaf(xv.w, pv.w, cx);
        }
        atomicAdd(&beta_sum[b * CC + c], sm);
        atomicAdd(&ctx_sum[b * CC + c], cx);
    }
}

// Pass 2: one block per batch — all the tiny matvec / LN / GELU / attention math.
__global__ __launch_bounds__(TPB) void finalize(
    const float* __restrict__ ws,
    const float* __restrict__ w_cm1,  const float* __restrict__ b_cm1,
    const float* __restrict__ ln_w,   const float* __restrict__ ln_b,
    const float* __restrict__ w_cm2,  const float* __restrict__ b_cm2,
    const float* __restrict__ w_net1, const float* __restrict__ w_net2,
    const float* __restrict__ w_fc,   const float* __restrict__ bn_w,
    const float* __restrict__ bn_b,   const float* __restrict__ bn_mean,
    const float* __restrict__ bn_var, const float* __restrict__ w_kfc,
    float* __restrict__ out)
{
    __shared__ __align__(16) float s_beta[CC];
    __shared__ __align__(16) float s_ctx[CC];
    __shared__ __align__(16) float s_t[128];
    __shared__ __align__(16) float s_out[CC];
    __shared__ float s_h[16];
    __shared__ float s_o2[8];
    __shared__ float s_red[4];
    __shared__ float s_scal[4];  // a, m, mu, rstd

    const float* beta_sum = ws + WS_BETA;
    const float* ctx_sum  = ws + WS_CTX;
    const float* Zsum     = ws + WS_Z;
    const float* msum     = ws + WS_M;

    const int b = blockIdx.x, tid = threadIdx.x;

    const float bc = beta_sum[b * CC + tid] * (1.f / 4096.f);
    const float cx = ctx_sum[b * CC + tid] / Zsum[b];
    s_beta[tid] = bc;
    s_ctx[tid]  = cx;

    // a = mean over channels of beta_c
    float av = bc;
    #pragma unroll
    for (int off = 32; off > 0; off >>= 1) av += __shfl_down(av, off, 64);
    if ((tid & 63) == 0) s_red[tid >> 6] = av;
    __syncthreads();
    if (tid == 0) {
        s_scal[0] = (s_red[0] + s_red[1] + s_red[2] + s_red[3]) * (1.f / 256.f);
        s_scal[1] = msum[b] * (1.f / 4096.f);
    }
    __syncthreads();

    // t = ctx @ w_cm1.T + b_cm1   [128]
    if (tid < 128) {
        const float4* wr = reinterpret_cast<const float4*>(w_cm1 + tid * 256);
        const float4* cr = reinterpret_cast<const float4*>(s_ctx);
        float acc = 0.f;
        #pragma unroll 4
        for (int i = 0; i < 64; ++i) {
            const float4 w = wr[i], c4 = cr[i];
            acc = fmaf(w.x, c4.x, acc); acc = fmaf(w.y, c4.y, acc);
            acc = fmaf(w.z, c4.z, acc); acc = fmaf(w.w, c4.w, acc);
        }
        s_t[tid] = acc + b_cm1[tid];
    }
    __syncthreads();

    // LayerNorm stats over 128 (wave 0)
    if (tid < 64) {
        float v = s_t[tid] + s_t[tid + 64];
        #pragma unroll
        for (int off = 32; off > 0; off >>= 1) v += __shfl_down(v, off, 64);
        float mu = __shfl(v, 0, 64) * (1.f / 128.f);
        const float d0 = s_t[tid] - mu, d1 = s_t[tid + 64] - mu;
        float vv = d0 * d0 + d1 * d1;
        #pragma unroll
        for (int off = 32; off > 0; off >>= 1) vv += __shfl_down(vv, off, 64);
        if (tid == 0) {
            s_scal[2] = mu;
            s_scal[3] = rsqrtf(vv * (1.f / 128.f) + 1e-5f);
        }
    }
    __syncthreads();

    // LN affine + exact GELU
    if (tid < 128) {
        float g = (s_t[tid] - s_scal[2]) * s_scal[3] * ln_w[tid] + ln_b[tid];
        g = 0.5f * g * (1.0f + erff(g * 0.70710678118654752f));
        s_t[tid] = g;
    }
    __syncthreads();

    // beta_g = g @ w_cm2.T + b_cm2 ; out = beta_c + beta_g + beta_s
    {
        const float4* wr = reinterpret_cast<const float4*>(w_cm2 + tid * 128);
        const float4* gr = reinterpret_cast<const float4*>(s_t);
        float acc = 0.f;
        #pragma unroll 4
        for (int i = 0; i < 32; ++i) {
            const float4 w = wr[i], g = gr[i];
            acc = fmaf(w.x, g.x, acc); acc = fmaf(w.y, g.y, acc);
            acc = fmaf(w.z, g.z, acc); acc = fmaf(w.w, g.w, acc);
        }
        const float bs = (tid & 1) ? s_scal[1] : s_scal[0];
        s_out[tid] = s_beta[tid] + acc + b_cm2[tid] + bs;
    }
    __syncthreads();

    // h = relu(out @ w_net1.T)   [16]
    if (tid < 16) {
        const float4* wr = reinterpret_cast<const float4*>(w_net1 + tid * 256);
        const float4* orr = reinterpret_cast<const float4*>(s_out);
        float acc = 0.f;
        #pragma unroll 4
        for (int i = 0; i < 64; ++i) {
            const float4 w = wr[i], o = orr[i];
            acc = fmaf(w.x, o.x, acc); acc = fmaf(w.y, o.y, acc);
            acc = fmaf(w.z, o.z, acc); acc = fmaf(w.w, o.w, acc);
        }
        s_h[tid] = fmaxf(acc, 0.f);
    }
    __syncthreads();

    // o2 = h @ w_net2.T   [8]
    if (tid < 8) {
        float acc = 0.f;
        #pragma unroll
        for (int jj = 0; jj < 16; ++jj) acc += s_h[jj] * w_net2[tid * 16 + jj];
        s_o2[tid] = acc;
    }
    __syncthreads();

    // kernel attention + final softmax (scalar, trivial)
    if (tid == 0) {
        float r[4];
        #pragma unroll
        for (int q = 0; q < 4; ++q) {
            float acc = 0.f;
            #pragma unroll
            for (int k = 0; k < 8; ++k) acc += s_o2[k] * w_fc[q * 8 + k];
            acc = (acc - bn_mean[q]) * rsqrtf(bn_var[q] + 1e-5f) * bn_w[q] + bn_b[q];
            r[q] = fmaxf(acc, 0.f);
        }
        float v[8], vmax = -3.4e38f;
        #pragma unroll
        for (int k = 0; k < 8; ++k) {
            float acc = 0.f;
            #pragma unroll
            for (int q = 0; q < 4; ++q) acc += r[q] * w_kfc[k * 4 + q];
            const float kr = 1.f / (1.f + expf(-acc));
            v[k] = s_o2[k] * kr * (1.f / 30.f);
            vmax = fmaxf(vmax, v[k]);
        }
        float zs = 0.f;
        #pragma unroll
        for (int k = 0; k < 8; ++k) { v[k] = expf(v[k] - vmax); zs += v[k]; }
        const float inv = 1.f / zs;
        #pragma unroll
        for (int k = 0; k < 8; ++k) out[b * 8 + k] = v[k] * inv;
    }
}

extern "C" void kernel_launch(void* const* d_in, const int* in_sizes, int n_in,
                              void* d_out, int out_size, void* d_ws, size_t ws_size,
                              hipStream_t stream) {
    const float* x       = (const float*)d_in[0];
    const float* w_mask  = (const float*)d_in[1];
    const float* b_mask  = (const float*)d_in[2];
    const float* w_cm1   = (const float*)d_in[3];
    const float* b_cm1   = (const float*)d_in[4];
    const float* ln_w    = (const float*)d_in[5];
    const float* ln_b    = (const float*)d_in[6];
    const float* w_cm2   = (const float*)d_in[7];
    const float* b_cm2   = (const float*)d_in[8];
    const float* w_net1  = (const float*)d_in[9];
    const float* w_net2  = (const float*)d_in[10];
    const float* w_fc    = (const float*)d_in[11];
    const float* bn_w    = (const float*)d_in[12];
    const float* bn_b    = (const float*)d_in[13];
    const float* bn_mean = (const float*)d_in[14];
    const float* bn_var  = (const float*)d_in[15];
    const float* w_kfc   = (const float*)d_in[16];
    float* out = (float*)d_out;
    float* ws  = (float*)d_ws;

    zero_ws<<<(WS_N + 255) / 256, 256, 0, stream>>>(ws, WS_N);
    pass1<<<BB * (HWQ / TILE), TPB, 0, stream>>>(x, w_mask, b_mask, ws);
    finalize<<<BB, TPB, 0, stream>>>(ws, w_cm1, b_cm1, ln_w, ln_b, w_cm2, b_cm2,
                                     w_net1, w_net2, w_fc, bn_w, bn_b, bn_mean,
                                     bn_var, w_kfc, out);
}